// Round 6
// baseline (372.164 us; speedup 1.0000x reference)
//
#include <hip/hip_runtime.h>
#include <math.h>

#define N_NODES 100000
#define N_EDGES 800000
#define F 128
#define SCAN_BLOCKS ((N_NODES + 255) / 256)   // 391

typedef __attribute__((ext_vector_type(8))) short short8;
typedef __attribute__((ext_vector_type(4))) float floatx4;

__device__ __forceinline__ unsigned short f2bf(float f) {
    unsigned u = __float_as_uint(f);
    u += 0x7fffu + ((u >> 16) & 1u);          // round-to-nearest-even
    return (unsigned short)(u >> 16);
}
__device__ __forceinline__ float bf_lo(unsigned u) { return __uint_as_float(u << 16); }
__device__ __forceinline__ float bf_hi(unsigned u) { return __uint_as_float(u & 0xffff0000u); }
__device__ __forceinline__ unsigned pack2(float a, float b) {
    return (unsigned)f2bf(a) | ((unsigned)f2bf(b) << 16);
}

// ---------------- prep: zero cnt + convert x to bf16 CHUNKED layout ----------------
// xb[c][node][16 bf16]: chunk c = features [16c, 16c+16). One thread per (node, chunk).

__global__ void k_prep(const float* __restrict__ x, unsigned* __restrict__ xb,
                       int* __restrict__ cnt) {
    int tid = blockIdx.x * blockDim.x + threadIdx.x;
    if (tid < N_NODES) cnt[tid] = 0;
    if (tid >= N_NODES * 8) return;
    int node = tid >> 3, c = tid & 7;
    const float4* xr = (const float4*)(x + (size_t)node * F + c * 16);
    float4 v0 = xr[0], v1 = xr[1], v2 = xr[2], v3 = xr[3];
    uint4 o0, o1;
    o0.x = pack2(v0.x, v0.y); o0.y = pack2(v0.z, v0.w);
    o0.z = pack2(v1.x, v1.y); o0.w = pack2(v1.z, v1.w);
    o1.x = pack2(v2.x, v2.y); o1.y = pack2(v2.z, v2.w);
    o1.z = pack2(v3.x, v3.y); o1.w = pack2(v3.z, v3.w);
    uint4* dst = (uint4*)(xb + ((size_t)c * N_NODES + node) * 8);
    dst[0] = o0; dst[1] = o1;
}

// ---------------- CSR build ----------------

__global__ void k_hist(const int* __restrict__ col, int* __restrict__ cnt) {
    int e = blockIdx.x * blockDim.x + threadIdx.x;
    if (e < N_EDGES) atomicAdd(&cnt[col[e]], 1);
}

// block-local exclusive scan of cnt -> rowptr, block totals -> bsum; fused dinv
__global__ void k_scan1(const int* __restrict__ cnt, int* __restrict__ rowptr,
                        int* __restrict__ bsum, float* __restrict__ dinv) {
    __shared__ int s[256];
    int t = threadIdx.x, i = blockIdx.x * 256 + t;
    int v = (i < N_NODES) ? cnt[i] : 0;
    if (i < N_NODES) dinv[i] = rsqrtf((float)v + 1.0f);   // +1 self-loop
    s[t] = v; __syncthreads();
#pragma unroll
    for (int off = 1; off < 256; off <<= 1) {
        int u = (t >= off) ? s[t - off] : 0;
        __syncthreads();
        s[t] += u; __syncthreads();
    }
    if (i < N_NODES) rowptr[i] = s[t] - v;      // exclusive
    if (t == 255) bsum[blockIdx.x] = s[255];
}

__global__ void k_scan2(int* __restrict__ bsum) {
    __shared__ int s[512];
    int t = threadIdx.x;
    int v = (t < SCAN_BLOCKS) ? bsum[t] : 0;
    s[t] = v; __syncthreads();
#pragma unroll
    for (int off = 1; off < 512; off <<= 1) {
        int u = (t >= off) ? s[t - off] : 0;
        __syncthreads();
        s[t] += u; __syncthreads();
    }
    if (t < SCAN_BLOCKS) bsum[t] = s[t] - v;    // exclusive
}

__global__ void k_scan3(int* __restrict__ rowptr, const int* __restrict__ bsum) {
    int i = blockIdx.x * blockDim.x + threadIdx.x;
    if (i < N_NODES) rowptr[i] += bsum[i >> 8];
    if (i == 0) rowptr[N_NODES] = N_EDGES;
}

// fill CSR; consumes cnt (atomicSub). Entry = top-15 bits of fp32 weight | 17-bit src idx.
__global__ void k_fill(const int* __restrict__ row, const int* __restrict__ col,
                       const int* __restrict__ rowptr, int* __restrict__ cnt,
                       const float* __restrict__ dinv, unsigned* __restrict__ csr) {
    int e = blockIdx.x * blockDim.x + threadIdx.x;
    if (e >= N_EDGES) return;
    int r = row[e], c = col[e];
    int pos = rowptr[c] + atomicSub(&cnt[c], 1) - 1;
    float w = dinv[r] * dinv[c];                 // in (0, 1]
    csr[pos] = (__float_as_uint(w) & 0xFFFE0000u) | (unsigned)r;
}

// ---------------- propagation: chunked L2-resident gather ----------------
// chunk = blockIdx % 8 pins each 3.2MB feature chunk to one XCD's L2.
// Wave = 8 nodes x 1 chunk: lane = sub*8 + f; sub walks its node's edges, 2-deep.

__global__ __launch_bounds__(256) void k_hop(const int* __restrict__ rowptr,
                                             const unsigned* __restrict__ csr,
                                             const float* __restrict__ dinv,
                                             const unsigned* __restrict__ src,
                                             unsigned* __restrict__ dst) {
    int wave = threadIdx.x >> 6, lane = threadIdx.x & 63;
    int chunk = blockIdx.x & 7;
    int grp = blockIdx.x >> 3;                       // 0..3124
    int node = (grp * 4 + wave) * 8 + (lane >> 3);   // exact: 100k nodes
    int f = lane & 7;
    const unsigned* sc = src + (size_t)chunk * N_NODES * 8;
    float s = dinv[node], ss = s * s;
    unsigned u = sc[(size_t)node * 8 + f];
    float a0 = ss * bf_lo(u), a1 = ss * bf_hi(u);    // self-loop term
    int e = rowptr[node], end = rowptr[node + 1];
    while (__ballot(e < end)) {
#pragma unroll
        for (int j = 0; j < 2; ++j) {
            bool p = (e + j) < end;
            unsigned ew = p ? csr[e + j] : 0u;       // w decodes to 0 when masked
            float w = __uint_as_float(ew & 0xFFFE0000u);
            unsigned v = p ? sc[(size_t)(ew & 0x1FFFFu) * 8 + f] : 0u;
            a0 = fmaf(w, bf_lo(v), a0);
            a1 = fmaf(w, bf_hi(v), a1);
        }
        e += 2;
    }
    dst[((size_t)chunk * N_NODES + node) * 8 + f] = pack2(a0, a1);  // 256B/wave coalesced
}

// ---------------- MFMA GEMM + bias + log_softmax (reads chunked h) ----------------

__global__ __launch_bounds__(256) void k_gemm_lsm_mfma(const unsigned short* __restrict__ h,
                                                       const float* __restrict__ W,
                                                       const float* __restrict__ b,
                                                       float* __restrict__ out) {
    int lane = threadIdx.x & 63;
    int wave = threadIdx.x >> 6;
    int m = lane & 15, quad = lane >> 4;

    // B fragment: lane holds B[k=quad*8+j][n=m] = W[16t+m][ks*32+quad*8+j]
    short8 bfr[8][4];
    float bv[8];
#pragma unroll
    for (int t = 0; t < 8; ++t) {
        bv[t] = b[16 * t + m];
        const float* wr = W + (size_t)(16 * t + m) * 128;
#pragma unroll
        for (int ks = 0; ks < 4; ++ks) {
            const float* wp = wr + ks * 32 + quad * 8;
            short8 v;
#pragma unroll
            for (int j = 0; j < 8; ++j) v[j] = (short)f2bf(wp[j]);
            bfr[t][ks] = v;
        }
    }

    const int ngroups = (N_NODES + 63) / 64;        // 1563 groups of 64 nodes
    for (int g = blockIdx.x; g < ngroups; g += gridDim.x) {
        int gbase = g * 64 + wave * 16;
        int nodeA = gbase + m;
        int node_c = nodeA < N_NODES ? nodeA : N_NODES - 1;
        short8 a[4];
        // k = ks*32 + quad*8 + j lives in chunk 2*ks + (quad>>1), offset (quad&1)*8
#pragma unroll
        for (int ks = 0; ks < 4; ++ks) {
            int c2 = 2 * ks + (quad >> 1);
            a[ks] = *(const short8*)(h + ((size_t)c2 * N_NODES + node_c) * 16 + (quad & 1) * 8);
        }
        floatx4 acc[8];
#pragma unroll
        for (int t = 0; t < 8; ++t) acc[t] = (floatx4){bv[t], bv[t], bv[t], bv[t]};
#pragma unroll
        for (int ks = 0; ks < 4; ++ks)
#pragma unroll
            for (int t = 0; t < 8; ++t)
                acc[t] = __builtin_amdgcn_mfma_f32_16x16x32_bf16(a[ks], bfr[t][ks], acc[t], 0, 0, 0);

        // D layout: row = gbase + quad*4 + r, col = 16t + m
#pragma unroll
        for (int r = 0; r < 4; ++r) {
            float mx = acc[0][r];
#pragma unroll
            for (int t = 1; t < 8; ++t) mx = fmaxf(mx, acc[t][r]);
#pragma unroll
            for (int msk = 1; msk < 16; msk <<= 1) mx = fmaxf(mx, __shfl_xor(mx, msk));
            float sm = 0.f;
#pragma unroll
            for (int t = 0; t < 8; ++t) sm += __expf(acc[t][r] - mx);
#pragma unroll
            for (int msk = 1; msk < 16; msk <<= 1) sm += __shfl_xor(sm, msk);
            float l = mx + __logf(sm);
            int rown = gbase + quad * 4 + r;
            if (rown < N_NODES) {
                float* op = out + (size_t)rown * 128 + m;
#pragma unroll
                for (int t = 0; t < 8; ++t) op[16 * t] = acc[t][r] - l;
            }
        }
    }
}

// ---------------- launch ----------------

extern "C" void kernel_launch(void* const* d_in, const int* in_sizes, int n_in,
                              void* d_out, int out_size, void* d_ws, size_t ws_size,
                              hipStream_t stream) {
    const float* x = (const float*)d_in[0];
    const float* W = (const float*)d_in[1];
    const float* b = (const float*)d_in[2];
    const int* edge = (const int*)d_in[3];
    const int* row = edge;             // source nodes j
    const int* col = edge + N_EDGES;   // target nodes i
    float* out = (float*)d_out;

    // workspace layout (4B word offsets)
    int*      cnt     = (int*)d_ws;                   // 100k
    int*      rowptr  = cnt + 102400;                 // 100k+1
    int*      bsum    = rowptr + 102400;              // 391
    float*    dinv    = (float*)(bsum + 1024);        // 100k
    unsigned* csr     = (unsigned*)(dinv + 102400);   // 800k = 3.2MB
    unsigned* xb      = csr + 819200;                 // 6.4M uints = 25.6MB (chunked)
    unsigned* h1b     = xb + 6400000;                 // 6.4M uints
    unsigned* h2b     = h1b + 6400000;                // 6.4M uints

    int nb_edges = (N_EDGES + 255) / 256;
    int nb_prep = (N_NODES * 8 + 255) / 256;          // 3125

    k_prep<<<nb_prep, 256, 0, stream>>>(x, xb, cnt);
    k_hist<<<nb_edges, 256, 0, stream>>>(col, cnt);
    k_scan1<<<SCAN_BLOCKS, 256, 0, stream>>>(cnt, rowptr, bsum, dinv);
    k_scan2<<<1, 512, 0, stream>>>(bsum);
    k_scan3<<<SCAN_BLOCKS, 256, 0, stream>>>(rowptr, bsum);
    k_fill<<<nb_edges, 256, 0, stream>>>(row, col, rowptr, cnt, dinv, csr);

    int hop_blocks = (N_NODES / 8) * 8 / 4;           // 25000: 4 waves/block, 8 nodes/wave
    k_hop<<<hop_blocks, 256, 0, stream>>>(rowptr, csr, dinv, xb, h1b);
    k_hop<<<hop_blocks, 256, 0, stream>>>(rowptr, csr, dinv, h1b, h2b);

    k_gemm_lsm_mfma<<<512, 256, 0, stream>>>((const unsigned short*)h2b, W, b, out);
}

// Round 7
// 353.298 us; speedup vs baseline: 1.0534x; 1.0534x over previous
//
#include <hip/hip_runtime.h>
#include <math.h>

#define N_NODES 100000
#define N_EDGES 800000
#define F 128
#define SCAN_BLOCKS ((N_NODES + 255) / 256)   // 391

typedef __attribute__((ext_vector_type(8))) short short8;
typedef __attribute__((ext_vector_type(4))) float floatx4;

__device__ __forceinline__ unsigned short f2bf(float f) {
    unsigned u = __float_as_uint(f);
    u += 0x7fffu + ((u >> 16) & 1u);          // round-to-nearest-even
    return (unsigned short)(u >> 16);
}
__device__ __forceinline__ float bf_lo(unsigned u) { return __uint_as_float(u << 16); }
__device__ __forceinline__ float bf_hi(unsigned u) { return __uint_as_float(u & 0xffff0000u); }
__device__ __forceinline__ unsigned pack2(float a, float b) {
    return (unsigned)f2bf(a) | ((unsigned)f2bf(b) << 16);
}

// ---------------- prep: zero cnt + convert x to bf16 CHUNKED layout ----------------
// xb[c][node][16 bf16]: chunk c = features [16c, 16c+16). One thread per (node, chunk).

__global__ void k_prep(const float* __restrict__ x, unsigned* __restrict__ xb,
                       int* __restrict__ cnt) {
    int tid = blockIdx.x * blockDim.x + threadIdx.x;
    if (tid < N_NODES) cnt[tid] = 0;
    if (tid >= N_NODES * 8) return;
    int node = tid >> 3, c = tid & 7;
    const float4* xr = (const float4*)(x + (size_t)node * F + c * 16);
    float4 v0 = xr[0], v1 = xr[1], v2 = xr[2], v3 = xr[3];
    uint4 o0, o1;
    o0.x = pack2(v0.x, v0.y); o0.y = pack2(v0.z, v0.w);
    o0.z = pack2(v1.x, v1.y); o0.w = pack2(v1.z, v1.w);
    o1.x = pack2(v2.x, v2.y); o1.y = pack2(v2.z, v2.w);
    o1.z = pack2(v3.x, v3.y); o1.w = pack2(v3.z, v3.w);
    uint4* dst = (uint4*)(xb + ((size_t)c * N_NODES + node) * 8);
    dst[0] = o0; dst[1] = o1;
}

// ---------------- CSR build ----------------

__global__ void k_hist(const int* __restrict__ col, int* __restrict__ cnt) {
    int e = blockIdx.x * blockDim.x + threadIdx.x;
    if (e < N_EDGES) atomicAdd(&cnt[col[e]], 1);
}

// block-local exclusive scan of cnt -> rowptr, block totals -> bsum; fused dinv
__global__ void k_scan1(const int* __restrict__ cnt, int* __restrict__ rowptr,
                        int* __restrict__ bsum, float* __restrict__ dinv) {
    __shared__ int s[256];
    int t = threadIdx.x, i = blockIdx.x * 256 + t;
    int v = (i < N_NODES) ? cnt[i] : 0;
    if (i < N_NODES) dinv[i] = rsqrtf((float)v + 1.0f);   // +1 self-loop
    s[t] = v; __syncthreads();
#pragma unroll
    for (int off = 1; off < 256; off <<= 1) {
        int u = (t >= off) ? s[t - off] : 0;
        __syncthreads();
        s[t] += u; __syncthreads();
    }
    if (i < N_NODES) rowptr[i] = s[t] - v;      // exclusive
    if (t == 255) bsum[blockIdx.x] = s[255];
}

__global__ void k_scan2(int* __restrict__ bsum) {
    __shared__ int s[512];
    int t = threadIdx.x;
    int v = (t < SCAN_BLOCKS) ? bsum[t] : 0;
    s[t] = v; __syncthreads();
#pragma unroll
    for (int off = 1; off < 512; off <<= 1) {
        int u = (t >= off) ? s[t - off] : 0;
        __syncthreads();
        s[t] += u; __syncthreads();
    }
    if (t < SCAN_BLOCKS) bsum[t] = s[t] - v;    // exclusive
}

__global__ void k_scan3(int* __restrict__ rowptr, const int* __restrict__ bsum) {
    int i = blockIdx.x * blockDim.x + threadIdx.x;
    if (i < N_NODES) rowptr[i] += bsum[i >> 8];
    if (i == 0) rowptr[N_NODES] = N_EDGES;
}

// fill CSR; consumes cnt (atomicSub). Entry = top-15 bits of fp32 weight | 17-bit src idx.
__global__ void k_fill(const int* __restrict__ row, const int* __restrict__ col,
                       const int* __restrict__ rowptr, int* __restrict__ cnt,
                       const float* __restrict__ dinv, unsigned* __restrict__ csr) {
    int e = blockIdx.x * blockDim.x + threadIdx.x;
    if (e >= N_EDGES) return;
    int r = row[e], c = col[e];
    int pos = rowptr[c] + atomicSub(&cnt[c], 1) - 1;
    float w = dinv[r] * dinv[c];                 // in (0, 1]
    csr[pos] = (__float_as_uint(w) & 0xFFFE0000u) | (unsigned)r;
}

// ---------------- propagation: chunked L2-resident gather, 8-deep MLP ----------------
// chunk = blockIdx % 8 pins each 3.2MB feature chunk to one XCD's L2 (verified R6:
// FETCH 104 -> 34 MB). Wave = 8 nodes x 8 lanes (uint = 2 bf16 per lane = 32B row).
// 8-deep unroll: 8 csr + 8 row loads in flight (~2.3 KB/wave) to kill the latency
// exposure that made the 2-deep version issue-starved. Exec-masked lanes in the
// predicated tail issue no memory requests, so over-run costs issue only.

__global__ __launch_bounds__(256) void k_hop(const int* __restrict__ rowptr,
                                             const unsigned* __restrict__ csr,
                                             const float* __restrict__ dinv,
                                             const unsigned* __restrict__ src,
                                             unsigned* __restrict__ dst) {
    int wave = threadIdx.x >> 6, lane = threadIdx.x & 63;
    int chunk = blockIdx.x & 7;
    int grp = blockIdx.x >> 3;                       // 0..3124
    int node = (grp * 4 + wave) * 8 + (lane >> 3);   // exact: 100k nodes
    int f = lane & 7;
    const unsigned* sc = src + (size_t)chunk * N_NODES * 8;
    float s = dinv[node], ss = s * s;
    unsigned u = sc[(size_t)node * 8 + f];
    float a0 = ss * bf_lo(u), a1 = ss * bf_hi(u);    // self-loop term
    int e = rowptr[node], end = rowptr[node + 1];
    while (__ballot(e < end)) {
#pragma unroll
        for (int j = 0; j < 8; ++j) {
            bool p = (e + j) < end;
            unsigned ew = p ? csr[e + j] : 0u;       // w decodes to 0 when masked
            float w = __uint_as_float(ew & 0xFFFE0000u);
            unsigned v = p ? sc[(size_t)(ew & 0x1FFFFu) * 8 + f] : 0u;
            a0 = fmaf(w, bf_lo(v), a0);
            a1 = fmaf(w, bf_hi(v), a1);
        }
        e += 8;
    }
    dst[((size_t)chunk * N_NODES + node) * 8 + f] = pack2(a0, a1);  // 256B/wave coalesced
}

// ---------------- MFMA GEMM + bias + log_softmax (reads chunked h) ----------------

__global__ __launch_bounds__(256) void k_gemm_lsm_mfma(const unsigned short* __restrict__ h,
                                                       const float* __restrict__ W,
                                                       const float* __restrict__ b,
                                                       float* __restrict__ out) {
    int lane = threadIdx.x & 63;
    int wave = threadIdx.x >> 6;
    int m = lane & 15, quad = lane >> 4;

    // B fragment: lane holds B[k=quad*8+j][n=m] = W[16t+m][ks*32+quad*8+j]
    short8 bfr[8][4];
    float bv[8];
#pragma unroll
    for (int t = 0; t < 8; ++t) {
        bv[t] = b[16 * t + m];
        const float* wr = W + (size_t)(16 * t + m) * 128;
#pragma unroll
        for (int ks = 0; ks < 4; ++ks) {
            const float* wp = wr + ks * 32 + quad * 8;
            short8 v;
#pragma unroll
            for (int j = 0; j < 8; ++j) v[j] = (short)f2bf(wp[j]);
            bfr[t][ks] = v;
        }
    }

    const int ngroups = (N_NODES + 63) / 64;        // 1563 groups of 64 nodes
    for (int g = blockIdx.x; g < ngroups; g += gridDim.x) {
        int gbase = g * 64 + wave * 16;
        int nodeA = gbase + m;
        int node_c = nodeA < N_NODES ? nodeA : N_NODES - 1;
        short8 a[4];
        // k = ks*32 + quad*8 + j lives in chunk 2*ks + (quad>>1), offset (quad&1)*8
#pragma unroll
        for (int ks = 0; ks < 4; ++ks) {
            int c2 = 2 * ks + (quad >> 1);
            a[ks] = *(const short8*)(h + ((size_t)c2 * N_NODES + node_c) * 16 + (quad & 1) * 8);
        }
        floatx4 acc[8];
#pragma unroll
        for (int t = 0; t < 8; ++t) acc[t] = (floatx4){bv[t], bv[t], bv[t], bv[t]};
#pragma unroll
        for (int ks = 0; ks < 4; ++ks)
#pragma unroll
            for (int t = 0; t < 8; ++t)
                acc[t] = __builtin_amdgcn_mfma_f32_16x16x32_bf16(a[ks], bfr[t][ks], acc[t], 0, 0, 0);

        // D layout: row = gbase + quad*4 + r, col = 16t + m
#pragma unroll
        for (int r = 0; r < 4; ++r) {
            float mx = acc[0][r];
#pragma unroll
            for (int t = 1; t < 8; ++t) mx = fmaxf(mx, acc[t][r]);
#pragma unroll
            for (int msk = 1; msk < 16; msk <<= 1) mx = fmaxf(mx, __shfl_xor(mx, msk));
            float sm = 0.f;
#pragma unroll
            for (int t = 0; t < 8; ++t) sm += __expf(acc[t][r] - mx);
#pragma unroll
            for (int msk = 1; msk < 16; msk <<= 1) sm += __shfl_xor(sm, msk);
            float l = mx + __logf(sm);
            int rown = gbase + quad * 4 + r;
            if (rown < N_NODES) {
                float* op = out + (size_t)rown * 128 + m;
#pragma unroll
                for (int t = 0; t < 8; ++t) op[16 * t] = acc[t][r] - l;
            }
        }
    }
}

// ---------------- launch ----------------

extern "C" void kernel_launch(void* const* d_in, const int* in_sizes, int n_in,
                              void* d_out, int out_size, void* d_ws, size_t ws_size,
                              hipStream_t stream) {
    const float* x = (const float*)d_in[0];
    const float* W = (const float*)d_in[1];
    const float* b = (const float*)d_in[2];
    const int* edge = (const int*)d_in[3];
    const int* row = edge;             // source nodes j
    const int* col = edge + N_EDGES;   // target nodes i
    float* out = (float*)d_out;

    // workspace layout (4B word offsets)
    int*      cnt     = (int*)d_ws;                   // 100k
    int*      rowptr  = cnt + 102400;                 // 100k+1
    int*      bsum    = rowptr + 102400;              // 391
    float*    dinv    = (float*)(bsum + 1024);        // 100k
    unsigned* csr     = (unsigned*)(dinv + 102400);   // 800k = 3.2MB
    unsigned* xb      = csr + 819200;                 // 6.4M uints = 25.6MB (chunked)
    unsigned* h1b     = xb + 6400000;                 // 6.4M uints
    unsigned* h2b     = h1b + 6400000;                // 6.4M uints

    int nb_edges = (N_EDGES + 255) / 256;
    int nb_prep = (N_NODES * 8 + 255) / 256;          // 3125

    k_prep<<<nb_prep, 256, 0, stream>>>(x, xb, cnt);
    k_hist<<<nb_edges, 256, 0, stream>>>(col, cnt);
    k_scan1<<<SCAN_BLOCKS, 256, 0, stream>>>(cnt, rowptr, bsum, dinv);
    k_scan2<<<1, 512, 0, stream>>>(bsum);
    k_scan3<<<SCAN_BLOCKS, 256, 0, stream>>>(rowptr, bsum);
    k_fill<<<nb_edges, 256, 0, stream>>>(row, col, rowptr, cnt, dinv, csr);

    int hop_blocks = (N_NODES / 8) * 8 / 4;           // 25000: 4 waves/block, 8 nodes/wave
    k_hop<<<hop_blocks, 256, 0, stream>>>(rowptr, csr, dinv, xb, h1b);
    k_hop<<<hop_blocks, 256, 0, stream>>>(rowptr, csr, dinv, h1b, h2b);

    k_gemm_lsm_mfma<<<512, 256, 0, stream>>>((const unsigned short*)h2b, W, b, out);
}

// Round 8
// 300.878 us; speedup vs baseline: 1.2369x; 1.1742x over previous
//
#include <hip/hip_runtime.h>
#include <math.h>

#define N_NODES 100000
#define N_EDGES 800000
#define F 128
#define SCAN_BLOCKS ((N_NODES + 255) / 256)   // 391
#define CSR_CAP (N_EDGES + 7 * N_NODES)       // 1.5M entries (8-padded worst case)

typedef __attribute__((ext_vector_type(8))) short short8;
typedef __attribute__((ext_vector_type(4))) float floatx4;

__device__ __forceinline__ unsigned short f2bf(float f) {
    unsigned u = __float_as_uint(f);
    u += 0x7fffu + ((u >> 16) & 1u);          // round-to-nearest-even
    return (unsigned short)(u >> 16);
}
__device__ __forceinline__ float bf_lo(unsigned u) { return __uint_as_float(u << 16); }
__device__ __forceinline__ float bf_hi(unsigned u) { return __uint_as_float(u & 0xffff0000u); }
__device__ __forceinline__ unsigned pack2(float a, float b) {
    return (unsigned)f2bf(a) | ((unsigned)f2bf(b) << 16);
}

// ---------------- prep: zero cnt + convert x to bf16 flat layout ----------------

__global__ void k_prep(const float4* __restrict__ x, uint2* __restrict__ xb,
                       int* __restrict__ cnt) {
    int i = blockIdx.x * blockDim.x + threadIdx.x;
    if (i < N_NODES) cnt[i] = 0;
    if (i < N_NODES * (F / 4)) {               // 3.2M float4 -> uint2 (4 bf16)
        float4 v = x[i];
        uint2 o; o.x = pack2(v.x, v.y); o.y = pack2(v.z, v.w);
        xb[i] = o;
    }
}

// ---------------- CSR build (rows padded to multiples of 8) ----------------

__global__ void k_hist(const int* __restrict__ col, int* __restrict__ cnt) {
    int e = blockIdx.x * blockDim.x + threadIdx.x;
    if (e < N_EDGES) atomicAdd(&cnt[col[e]], 1);
}

// exclusive scan of PADDED counts -> rowptr; block totals -> bsum; fused dinv.
// i == N_NODES also gets its local prefix so scan3 can finalize rowptr[N].
__global__ void k_scan1(const int* __restrict__ cnt, int* __restrict__ rowptr,
                        int* __restrict__ bsum, float* __restrict__ dinv) {
    __shared__ int s[256];
    int t = threadIdx.x, i = blockIdx.x * 256 + t;
    int v = 0;
    if (i < N_NODES) {
        int c = cnt[i];
        dinv[i] = rsqrtf((float)c + 1.0f);     // +1 self-loop
        v = (c + 7) & ~7;                      // pad row to multiple of 8
    }
    s[t] = v; __syncthreads();
#pragma unroll
    for (int off = 1; off < 256; off <<= 1) {
        int u = (t >= off) ? s[t - off] : 0;
        __syncthreads();
        s[t] += u; __syncthreads();
    }
    if (i <= N_NODES) rowptr[i] = s[t] - v;    // exclusive (i==N: local total prefix)
    if (t == 255) bsum[blockIdx.x] = s[255];
}

// per-block private prefix of bsum (merged old scan2+scan3): one launch
__global__ void k_scan3(int* __restrict__ rowptr, const int* __restrict__ bsum) {
    __shared__ int s[256];
    int b = blockIdx.x, t = threadIdx.x;
    int p = 0;
    for (int k = t; k < b; k += 256) p += bsum[k];
    s[t] = p; __syncthreads();
#pragma unroll
    for (int off = 128; off; off >>= 1) {
        if (t < off) s[t] += s[t + off];
        __syncthreads();
    }
    int P = s[0];
    int i = b * 256 + t;
    if (i <= N_NODES) rowptr[i] += P;
}

// fill CSR; consumes cnt (atomicSub). Pad slots remain zero ({src=0, w=0.0}).
__global__ void k_fill(const int* __restrict__ row, const int* __restrict__ col,
                       const int* __restrict__ rowptr, int* __restrict__ cnt,
                       const float* __restrict__ dinv, uint2* __restrict__ csr2) {
    int e = blockIdx.x * blockDim.x + threadIdx.x;
    if (e >= N_EDGES) return;
    int r = row[e], c = col[e];
    int pos = rowptr[c] + atomicSub(&cnt[c], 1) - 1;
    uint2 o; o.x = (unsigned)r; o.y = __float_as_uint(dinv[r] * dinv[c]);
    csr2[pos] = o;
}

// ---------------- propagation: flat bf16 gather, 2 nodes/wave, exact 8-deep ----------------
// Rows padded to x8 -> no predication, no ballot, no tail. 16 row-loads (4KB)
// in flight per wave. Pad entries contribute 0.0 * row[0].

__global__ __launch_bounds__(256) void k_hop(const int* __restrict__ rowptr,
                                             const uint2* __restrict__ csr2,
                                             const float* __restrict__ dinv,
                                             const uint2* __restrict__ src,
                                             uint2* __restrict__ dst) {
    int wv = (blockIdx.x * blockDim.x + threadIdx.x) >> 6;
    int lane = threadIdx.x & 63;
    int half = lane >> 5, off = lane & 31;
    int node = wv * 2 + half;                       // 50k waves exact
    if (node >= N_NODES) return;
    float s = dinv[node], ss = s * s;
    uint2 u = src[(size_t)node * 32 + off];
    float a0 = ss * bf_lo(u.x), a1 = ss * bf_hi(u.x);
    float a2 = ss * bf_lo(u.y), a3 = ss * bf_hi(u.y);
    int e = rowptr[node], end = rowptr[node + 1];   // end-e is a multiple of 8
    for (; e < end; e += 8) {
#pragma unroll
        for (int j = 0; j < 8; ++j) {
            uint2 ew = csr2[e + j];
            float w = __uint_as_float(ew.y);
            uint2 v = src[(size_t)ew.x * 32 + off];
            a0 = fmaf(w, bf_lo(v.x), a0); a1 = fmaf(w, bf_hi(v.x), a1);
            a2 = fmaf(w, bf_lo(v.y), a2); a3 = fmaf(w, bf_hi(v.y), a3);
        }
    }
    uint2 o; o.x = pack2(a0, a1); o.y = pack2(a2, a3);
    dst[(size_t)node * 32 + off] = o;
}

// ---------------- MFMA GEMM + bias + log_softmax (flat h) ----------------

__global__ __launch_bounds__(256) void k_gemm_lsm_mfma(const unsigned short* __restrict__ h,
                                                       const float* __restrict__ W,
                                                       const float* __restrict__ b,
                                                       float* __restrict__ out) {
    int lane = threadIdx.x & 63;
    int wave = threadIdx.x >> 6;
    int m = lane & 15, quad = lane >> 4;

    // B fragment: lane holds B[k=quad*8+j][n=m] = W[16t+m][ks*32+quad*8+j]
    short8 bfr[8][4];
    float bv[8];
#pragma unroll
    for (int t = 0; t < 8; ++t) {
        bv[t] = b[16 * t + m];
        const float* wr = W + (size_t)(16 * t + m) * 128;
#pragma unroll
        for (int ks = 0; ks < 4; ++ks) {
            const float* wp = wr + ks * 32 + quad * 8;
            short8 v;
#pragma unroll
            for (int j = 0; j < 8; ++j) v[j] = (short)f2bf(wp[j]);
            bfr[t][ks] = v;
        }
    }

    const int ngroups = (N_NODES + 63) / 64;        // 1563 groups of 64 nodes
    for (int g = blockIdx.x; g < ngroups; g += gridDim.x) {
        int gbase = g * 64 + wave * 16;
        int nodeA = gbase + m;
        int node_c = nodeA < N_NODES ? nodeA : N_NODES - 1;
        short8 a[4];
#pragma unroll
        for (int ks = 0; ks < 4; ++ks)
            a[ks] = *(const short8*)(h + (size_t)node_c * 128 + ks * 32 + quad * 8);
        floatx4 acc[8];
#pragma unroll
        for (int t = 0; t < 8; ++t) acc[t] = (floatx4){bv[t], bv[t], bv[t], bv[t]};
#pragma unroll
        for (int ks = 0; ks < 4; ++ks)
#pragma unroll
            for (int t = 0; t < 8; ++t)
                acc[t] = __builtin_amdgcn_mfma_f32_16x16x32_bf16(a[ks], bfr[t][ks], acc[t], 0, 0, 0);

        // D layout: row = gbase + quad*4 + r, col = 16t + m
#pragma unroll
        for (int r = 0; r < 4; ++r) {
            float mx = acc[0][r];
#pragma unroll
            for (int t = 1; t < 8; ++t) mx = fmaxf(mx, acc[t][r]);
#pragma unroll
            for (int msk = 1; msk < 16; msk <<= 1) mx = fmaxf(mx, __shfl_xor(mx, msk));
            float sm = 0.f;
#pragma unroll
            for (int t = 0; t < 8; ++t) sm += __expf(acc[t][r] - mx);
#pragma unroll
            for (int msk = 1; msk < 16; msk <<= 1) sm += __shfl_xor(sm, msk);
            float l = mx + __logf(sm);
            int rown = gbase + quad * 4 + r;
            if (rown < N_NODES) {
                float* op = out + (size_t)rown * 128 + m;
#pragma unroll
                for (int t = 0; t < 8; ++t) op[16 * t] = acc[t][r] - l;
            }
        }
    }
}

// ---------------- launch ----------------

extern "C" void kernel_launch(void* const* d_in, const int* in_sizes, int n_in,
                              void* d_out, int out_size, void* d_ws, size_t ws_size,
                              hipStream_t stream) {
    const float* x = (const float*)d_in[0];
    const float* W = (const float*)d_in[1];
    const float* b = (const float*)d_in[2];
    const int* edge = (const int*)d_in[3];
    const int* row = edge;             // source nodes j
    const int* col = edge + N_EDGES;   // target nodes i
    float* out = (float*)d_out;

    // workspace layout (4B word offsets)
    int*   cnt     = (int*)d_ws;                      // 100k
    int*   rowptr  = cnt + 102400;                    // 100k+1 (padded-exclusive)
    int*   bsum    = rowptr + 102400;                 // 391
    float* dinv    = (float*)(bsum + 1024);           // 100k
    uint2* csr2    = (uint2*)(dinv + 102400);         // 1.5M uint2 = 12 MB
    uint2* xb      = csr2 + CSR_CAP;                  // 3.2M uint2 = 25.6 MB
    uint2* h1b     = xb + 3276800;                    // 3.2M uint2
    uint2* h2b     = xb;                              // reuse: xb dead after hop 1

    int nb_edges = (N_EDGES + 255) / 256;
    int nb_prep = (N_NODES * (F / 4) + 255) / 256;    // 12500

    hipMemsetAsync(csr2, 0, (size_t)CSR_CAP * 8, stream);   // pad slots = {0, 0.0f}
    k_prep<<<nb_prep, 256, 0, stream>>>((const float4*)x, xb, cnt);
    k_hist<<<nb_edges, 256, 0, stream>>>(col, cnt);
    k_scan1<<<SCAN_BLOCKS, 256, 0, stream>>>(cnt, rowptr, bsum, dinv);
    k_scan3<<<SCAN_BLOCKS, 256, 0, stream>>>(rowptr, bsum);
    k_fill<<<nb_edges, 256, 0, stream>>>(row, col, rowptr, cnt, dinv, csr2);

    int hop_blocks = (N_NODES / 2 * 64) / 256;        // 12500: one wave per 2 nodes
    k_hop<<<hop_blocks, 256, 0, stream>>>(rowptr, csr2, dinv, xb, h1b);
    k_hop<<<hop_blocks, 256, 0, stream>>>(rowptr, csr2, dinv, h1b, h2b);

    k_gemm_lsm_mfma<<<512, 256, 0, stream>>>((const unsigned short*)h2b, W, b, out);
}

// Round 9
// 293.540 us; speedup vs baseline: 1.2678x; 1.0250x over previous
//
#include <hip/hip_runtime.h>
#include <math.h>

#define N_NODES 100000
#define N_EDGES 800000
#define F 128
#define SCAN_BLOCKS ((N_NODES + 255) / 256)   // 391
#define CSR_CAP (N_EDGES + 7 * N_NODES)       // 1.5M entries (8-padded worst case)

typedef __attribute__((ext_vector_type(8))) short short8;
typedef __attribute__((ext_vector_type(4))) float floatx4;

__device__ __forceinline__ unsigned short f2bf(float f) {
    unsigned u = __float_as_uint(f);
    u += 0x7fffu + ((u >> 16) & 1u);          // round-to-nearest-even
    return (unsigned short)(u >> 16);
}
__device__ __forceinline__ float bf_lo(unsigned u) { return __uint_as_float(u << 16); }
__device__ __forceinline__ float bf_hi(unsigned u) { return __uint_as_float(u & 0xffff0000u); }
__device__ __forceinline__ unsigned pack2(float a, float b) {
    return (unsigned)f2bf(a) | ((unsigned)f2bf(b) << 16);
}

// ---------------- CSR build ----------------

__global__ void k_hist(const int* __restrict__ col, int* __restrict__ cnt) {
    int e = blockIdx.x * blockDim.x + threadIdx.x;
    if (e < N_EDGES) atomicAdd(&cnt[col[e]], 1);
}

// exclusive scan of PADDED counts -> rowptr; block totals -> bsum; dinv & dinv^2.
__global__ void k_scan1(const int* __restrict__ cnt, int* __restrict__ rowptr,
                        int* __restrict__ bsum, float* __restrict__ dinv,
                        float* __restrict__ dinv2) {
    __shared__ int s[256];
    int t = threadIdx.x, i = blockIdx.x * 256 + t;
    int v = 0;
    if (i < N_NODES) {
        int c = cnt[i];
        float d = rsqrtf((float)c + 1.0f);     // +1 self-loop
        dinv[i] = d; dinv2[i] = d * d;
        v = (c + 7) & ~7;                      // pad row to multiple of 8
    }
    s[t] = v; __syncthreads();
#pragma unroll
    for (int off = 1; off < 256; off <<= 1) {
        int u = (t >= off) ? s[t - off] : 0;
        __syncthreads();
        s[t] += u; __syncthreads();
    }
    if (i <= N_NODES) rowptr[i] = s[t] - v;    // exclusive (i==N: local total prefix)
    if (t == 255) bsum[blockIdx.x] = s[255];
}

// per-block private prefix of bsum: one launch finalize
__global__ void k_scan3(int* __restrict__ rowptr, const int* __restrict__ bsum) {
    __shared__ int s[256];
    int b = blockIdx.x, t = threadIdx.x;
    int p = 0;
    for (int k = t; k < b; k += 256) p += bsum[k];
    s[t] = p; __syncthreads();
#pragma unroll
    for (int off = 128; off; off >>= 1) {
        if (t < off) s[t] += s[t + off];
        __syncthreads();
    }
    int P = s[0];
    int i = b * 256 + t;
    if (i <= N_NODES) rowptr[i] += P;
}

// prep: xb[(v+1)] = bf16(dinv[v] * x[v])  (shifted rows; row 0 = zeros).
// Also zeroes row 0 of h1b. Runs after scan1 (needs dinv).
__global__ void k_prep(const float4* __restrict__ x, const float* __restrict__ dinv,
                       uint2* __restrict__ xb, uint2* __restrict__ h1b) {
    int i = blockIdx.x * blockDim.x + threadIdx.x;
    if (i < 32) { xb[i] = (uint2){0u, 0u}; h1b[i] = (uint2){0u, 0u}; }
    if (i >= N_NODES * 32) return;
    int node = i >> 5;
    float d = dinv[node];
    float4 v = x[i];
    uint2 o; o.x = pack2(d * v.x, d * v.y); o.y = pack2(d * v.z, d * v.w);
    xb[i + 32] = o;                            // row node+1
}

// fill CSR; consumes cnt (atomicSub). Entry = src index + 1 (4B).
// Pad slots stay 0 -> point at the zero row.
__global__ void k_fill(const int* __restrict__ row, const int* __restrict__ col,
                       const int* __restrict__ rowptr, int* __restrict__ cnt,
                       unsigned* __restrict__ csr) {
    int e = blockIdx.x * blockDim.x + threadIdx.x;
    if (e >= N_EDGES) return;
    int r = row[e], c = col[e];
    int pos = rowptr[c] + atomicSub(&cnt[c], 1) - 1;
    csr[pos] = (unsigned)(r + 1);
}

// ---------------- propagation: weight-free gather, 2 nodes/wave, exact 8-deep ----------------
// acc = y[c] + sum y[r]; out = scale[c] * acc  (scale = dinv^2 for hop1 -> y1,
// dinv for hop2 -> h2). Rows shifted +1; pad entries hit zero row 0 (L1-hot).

__global__ __launch_bounds__(256) void k_hop(const int* __restrict__ rowptr,
                                             const unsigned* __restrict__ csr,
                                             const float* __restrict__ scale,
                                             const uint2* __restrict__ src,
                                             uint2* __restrict__ dst) {
    int wv = (blockIdx.x * blockDim.x + threadIdx.x) >> 6;
    int lane = threadIdx.x & 63;
    int half = lane >> 5, off = lane & 31;
    int node = wv * 2 + half;                       // 50k waves exact
    if (node >= N_NODES) return;
    uint2 u = src[(size_t)(node + 1) * 32 + off];   // own (pre-scaled) row
    float a0 = bf_lo(u.x), a1 = bf_hi(u.x);
    float a2 = bf_lo(u.y), a3 = bf_hi(u.y);
    int e = rowptr[node], end = rowptr[node + 1];   // end-e is a multiple of 8
    for (; e < end; e += 8) {
        const uint4* cp = (const uint4*)(csr + e);  // 16B-aligned (8-padded rows)
        uint4 c0 = cp[0], c1 = cp[1];               // 8 indices, broadcast loads
        unsigned idx[8] = {c0.x, c0.y, c0.z, c0.w, c1.x, c1.y, c1.z, c1.w};
#pragma unroll
        for (int j = 0; j < 8; ++j) {
            uint2 v = src[(size_t)idx[j] * 32 + off];
            a0 += bf_lo(v.x); a1 += bf_hi(v.x);
            a2 += bf_lo(v.y); a3 += bf_hi(v.y);
        }
    }
    float s = scale[node];
    uint2 o; o.x = pack2(s * a0, s * a1); o.y = pack2(s * a2, s * a3);
    dst[(size_t)(node + 1) * 32 + off] = o;
}

// ---------------- MFMA GEMM + bias + log_softmax ----------------

__global__ __launch_bounds__(256) void k_gemm_lsm_mfma(const unsigned short* __restrict__ h,
                                                       const float* __restrict__ W,
                                                       const float* __restrict__ b,
                                                       float* __restrict__ out) {
    int lane = threadIdx.x & 63;
    int wave = threadIdx.x >> 6;
    int m = lane & 15, quad = lane >> 4;

    // B fragment: lane holds B[k=quad*8+j][n=m] = W[16t+m][ks*32+quad*8+j]
    short8 bfr[8][4];
    float bv[8];
#pragma unroll
    for (int t = 0; t < 8; ++t) {
        bv[t] = b[16 * t + m];
        const float* wr = W + (size_t)(16 * t + m) * 128;
#pragma unroll
        for (int ks = 0; ks < 4; ++ks) {
            const float* wp = wr + ks * 32 + quad * 8;
            short8 v;
#pragma unroll
            for (int j = 0; j < 8; ++j) v[j] = (short)f2bf(wp[j]);
            bfr[t][ks] = v;
        }
    }

    const int ngroups = (N_NODES + 63) / 64;        // 1563 groups of 64 nodes
    for (int g = blockIdx.x; g < ngroups; g += gridDim.x) {
        int gbase = g * 64 + wave * 16;
        int nodeA = gbase + m;
        int node_c = nodeA < N_NODES ? nodeA : N_NODES - 1;
        short8 a[4];
#pragma unroll
        for (int ks = 0; ks < 4; ++ks)
            a[ks] = *(const short8*)(h + (size_t)node_c * 128 + ks * 32 + quad * 8);
        floatx4 acc[8];
#pragma unroll
        for (int t = 0; t < 8; ++t) acc[t] = (floatx4){bv[t], bv[t], bv[t], bv[t]};
#pragma unroll
        for (int ks = 0; ks < 4; ++ks)
#pragma unroll
            for (int t = 0; t < 8; ++t)
                acc[t] = __builtin_amdgcn_mfma_f32_16x16x32_bf16(a[ks], bfr[t][ks], acc[t], 0, 0, 0);

        // D layout: row = gbase + quad*4 + r, col = 16t + m
#pragma unroll
        for (int r = 0; r < 4; ++r) {
            float mx = acc[0][r];
#pragma unroll
            for (int t = 1; t < 8; ++t) mx = fmaxf(mx, acc[t][r]);
#pragma unroll
            for (int msk = 1; msk < 16; msk <<= 1) mx = fmaxf(mx, __shfl_xor(mx, msk));
            float sm = 0.f;
#pragma unroll
            for (int t = 0; t < 8; ++t) sm += __expf(acc[t][r] - mx);
#pragma unroll
            for (int msk = 1; msk < 16; msk <<= 1) sm += __shfl_xor(sm, msk);
            float l = mx + __logf(sm);
            int rown = gbase + quad * 4 + r;
            if (rown < N_NODES) {
                float* op = out + (size_t)rown * 128 + m;
#pragma unroll
                for (int t = 0; t < 8; ++t) op[16 * t] = acc[t][r] - l;
            }
        }
    }
}

// ---------------- launch ----------------

extern "C" void kernel_launch(void* const* d_in, const int* in_sizes, int n_in,
                              void* d_out, int out_size, void* d_ws, size_t ws_size,
                              hipStream_t stream) {
    const float* x = (const float*)d_in[0];
    const float* W = (const float*)d_in[1];
    const float* b = (const float*)d_in[2];
    const int* edge = (const int*)d_in[3];
    const int* row = edge;             // source nodes j
    const int* col = edge + N_EDGES;   // target nodes i
    float* out = (float*)d_out;

    // workspace layout (4B word offsets); cnt adjacent to csr -> single memset
    int*      rowptr = (int*)d_ws;                    // 100k+1
    int*      bsum   = rowptr + 102400;               // 391
    float*    dinv   = (float*)(bsum + 1024);         // 100k
    float*    dinv2  = dinv + 102400;                 // 100k
    int*      cnt    = (int*)(dinv2 + 102400);        // 100k   } one memset
    unsigned* csr    = (unsigned*)(cnt + 102400);     // 1.5M   } (6.4 MB)
    uint2*    xb     = (uint2*)(csr + CSR_CAP);       // (N+1)*32 uint2 = 25.6 MB
    uint2*    h1b    = xb + 32 * (N_NODES + 1);       // (N+1)*32 uint2
    uint2*    h2b    = xb;                            // reuse: xb dead after hop 1

    int nb_edges = (N_EDGES + 255) / 256;
    int nb_prep = (N_NODES * 32 + 255) / 256;         // 12500

    hipMemsetAsync(cnt, 0, (size_t)(102400 + CSR_CAP) * 4, stream);
    k_hist<<<nb_edges, 256, 0, stream>>>(col, cnt);
    k_scan1<<<SCAN_BLOCKS, 256, 0, stream>>>(cnt, rowptr, bsum, dinv, dinv2);
    k_scan3<<<SCAN_BLOCKS, 256, 0, stream>>>(rowptr, bsum);
    k_prep<<<nb_prep, 256, 0, stream>>>((const float4*)x, dinv, xb, h1b);
    k_fill<<<nb_edges, 256, 0, stream>>>(row, col, rowptr, cnt, csr);

    int hop_blocks = (N_NODES / 2 * 64) / 256;        // 12500: one wave per 2 nodes
    k_hop<<<hop_blocks, 256, 0, stream>>>(rowptr, csr, dinv2, xb, h1b);   // -> y1
    k_hop<<<hop_blocks, 256, 0, stream>>>(rowptr, csr, dinv, h1b, h2b);   // -> h2

    k_gemm_lsm_mfma<<<512, 256, 0, stream>>>((const unsigned short*)(h2b + 32), W, b, out);
}